// Round 1
// baseline (353.649 us; speedup 1.0000x reference)
//
#include <hip/hip_runtime.h>
#include <math.h>

#define N_PTS 2048
#define I_DIM 16
#define H_DIM 64
#define O_DIM 64
#define NCUTS 8
#define NGROUPS 4
#define GN_EPS 1e-5f

// ---------------------------------------------------------------------------
// k1: input MLP  f = lrelu(lrelu(features @ W1^T + b1) @ W2^T + b2)
// block = 256 threads = 4 points x 64 channels
// ---------------------------------------------------------------------------
__global__ __launch_bounds__(256) void k_in_mlp(
    const float* __restrict__ features, const float* __restrict__ W1,
    const float* __restrict__ b1, const float* __restrict__ W2,
    const float* __restrict__ b2, float* __restrict__ out)
{
    __shared__ float f0s[4][H_DIM];
    int tid = threadIdx.x;
    int pl = tid >> 6, h = tid & 63;
    int n = blockIdx.x * 4 + pl;
    const float* fr = features + n * I_DIM;
    float s = b1[h];
    #pragma unroll
    for (int i = 0; i < I_DIM; ++i) s = fmaf(fr[i], W1[h * I_DIM + i], s);
    s = s > 0.f ? s : 0.2f * s;
    f0s[pl][h] = s;
    __syncthreads();
    float t = b2[h];
    #pragma unroll
    for (int k = 0; k < H_DIM; ++k) t = fmaf(f0s[pl][k], W2[h * H_DIM + k], t);
    t = t > 0.f ? t : 0.2f * t;
    out[n * H_DIM + h] = t;
}

// ---------------------------------------------------------------------------
// k2: group norm over (channels_in_group x ALL points), 1 block per group.
// x: (N, 64) row-major. Group g covers channels [16g, 16g+16).
// ---------------------------------------------------------------------------
__global__ __launch_bounds__(1024) void k_gnorm(
    const float* __restrict__ x, const float* __restrict__ w,
    const float* __restrict__ b, float* __restrict__ out)
{
    const int CPG = H_DIM / NGROUPS;          // 16
    const int TOT = CPG * N_PTS;              // 32768
    int g = blockIdx.x;
    int tid = threadIdx.x;
    float sum = 0.f, sq = 0.f;
    for (int idx = tid; idx < TOT; idx += 1024) {
        int ch = g * CPG + (idx & (CPG - 1));
        int n  = idx >> 4;
        float v = x[n * H_DIM + ch];
        sum += v; sq += v * v;
    }
    #pragma unroll
    for (int off = 32; off >= 1; off >>= 1) {
        sum += __shfl_down(sum, off);
        sq  += __shfl_down(sq , off);
    }
    __shared__ float ssum[16], ssq[16];
    __shared__ float mean_s, rstd_s;
    int lane = tid & 63, wv = tid >> 6;
    if (lane == 0) { ssum[wv] = sum; ssq[wv] = sq; }
    __syncthreads();
    if (tid == 0) {
        float S = 0.f, Q = 0.f;
        #pragma unroll
        for (int i = 0; i < 16; ++i) { S += ssum[i]; Q += ssq[i]; }
        float m   = S / (float)TOT;
        float var = Q / (float)TOT - m * m;
        mean_s = m;
        rstd_s = rsqrtf(var + GN_EPS);
    }
    __syncthreads();
    float m = mean_s, r = rstd_s;
    for (int idx = tid; idx < TOT; idx += 1024) {
        int ch = g * CPG + (idx & (CPG - 1));
        int n  = idx >> 4;
        float v = x[n * H_DIM + ch];
        out[n * H_DIM + ch] = (v - m) * r * w[ch] + b[ch];
    }
}

// ---------------------------------------------------------------------------
// k3: the N^2 pairwise windowed conv.
// One block per output point i; 256 threads split j; acc[64] in VGPRs.
// out[i,ch] = sum_j win(i,j) * relu(w2[ch,:].h(i,j) + b2[ch]) * f[j,ch]
// ---------------------------------------------------------------------------
__global__ __launch_bounds__(256) void k_conv(
    const float* __restrict__ points, const float* __restrict__ nuv,
    const float* __restrict__ cw1, const float* __restrict__ cb1,
    const float* __restrict__ cw2, const float* __restrict__ cb2,
    const float* __restrict__ fn, float* __restrict__ out)
{
    const float SC = 0.70710678118654752f;   // 1/sqrt(2), RADIUS=1
    int i = blockIdx.x;
    int tid = threadIdx.x;

    float pix = points[i * 3 + 0] * SC;
    float piy = points[i * 3 + 1] * SC;
    float piz = points[i * 3 + 2] * SC;
    float nv[9];
    #pragma unroll
    for (int a = 0; a < 9; ++a) nv[a] = nuv[i * 9 + a];

    float w1[NCUTS][3], bb1[NCUTS];
    #pragma unroll
    for (int c = 0; c < NCUTS; ++c) {
        w1[c][0] = cw1[c * 3 + 0];
        w1[c][1] = cw1[c * 3 + 1];
        w1[c][2] = cw1[c * 3 + 2];
        bb1[c]   = cb1[c];
    }

    float acc[H_DIM];
    #pragma unroll
    for (int d = 0; d < H_DIM; ++d) acc[d] = 0.f;

    for (int j = tid; j < N_PTS; j += 256) {
        float dx = points[j * 3 + 0] * SC - pix;
        float dy = points[j * 3 + 1] * SC - piy;
        float dz = points[j * 3 + 2] * SC - piz;
        float njx = nuv[j * 9 + 0], njy = nuv[j * 9 + 1], njz = nuv[j * 9 + 2];
        float nd = nv[0] * njx + nv[1] * njy + nv[2] * njz;
        float tt = 2.f - nd;
        float d2 = (dx * dx + dy * dy + dz * dz) * tt * tt;
        float win = __expf(-d2);
        float P0 = nv[0] * dx + nv[1] * dy + nv[2] * dz;
        float P1 = nv[3] * dx + nv[4] * dy + nv[5] * dz;
        float P2 = nv[6] * dx + nv[7] * dy + nv[8] * dz;
        float h[NCUTS];
        #pragma unroll
        for (int c = 0; c < NCUTS; ++c) {
            float v = fmaf(P0, w1[c][0], fmaf(P1, w1[c][1], fmaf(P2, w1[c][2], bb1[c])));
            h[c] = v > 0.f ? v : 0.f;
        }
        const float* fj = fn + j * H_DIM;
        #pragma unroll
        for (int d = 0; d < H_DIM; ++d) {
            float x = cb2[d];
            #pragma unroll
            for (int c = 0; c < NCUTS; ++c) x = fmaf(h[c], cw2[d * NCUTS + c], x);
            x = x > 0.f ? x : 0.f;
            acc[d] = fmaf(win * x, fj[d], acc[d]);
        }
    }

    // reduce acc[64] across 256 threads: butterfly within wave, LDS across waves
    #pragma unroll
    for (int d = 0; d < H_DIM; ++d) {
        float v = acc[d];
        v += __shfl_xor(v, 1);
        v += __shfl_xor(v, 2);
        v += __shfl_xor(v, 4);
        v += __shfl_xor(v, 8);
        v += __shfl_xor(v, 16);
        v += __shfl_xor(v, 32);
        acc[d] = v;
    }
    __shared__ float red[4][H_DIM];
    int lane = tid & 63, wv = tid >> 6;
    if (lane == 0) {
        #pragma unroll
        for (int d = 0; d < H_DIM; ++d) red[wv][d] = acc[d];
    }
    __syncthreads();
    if (tid < H_DIM) {
        float v = red[0][tid] + red[1][tid] + red[2][tid] + red[3][tid];
        out[i * H_DIM + tid] = v;
    }
}

// ---------------------------------------------------------------------------
// k4: output MLP  g = lrelu(lrelu(fmid @ Wo1^T + bo1) @ Wo2^T + bo2)
// ---------------------------------------------------------------------------
__global__ __launch_bounds__(256) void k_out_mlp(
    const float* __restrict__ fin, const float* __restrict__ W1,
    const float* __restrict__ b1, const float* __restrict__ W2,
    const float* __restrict__ b2, float* __restrict__ out)
{
    __shared__ float t1s[4][O_DIM];
    int tid = threadIdx.x;
    int pl = tid >> 6, o = tid & 63;
    int n = blockIdx.x * 4 + pl;
    const float* fr = fin + n * H_DIM;
    float s = b1[o];
    #pragma unroll
    for (int k = 0; k < H_DIM; ++k) s = fmaf(fr[k], W1[o * H_DIM + k], s);
    s = s > 0.f ? s : 0.2f * s;
    t1s[pl][o] = s;
    __syncthreads();
    float t = b2[o];
    #pragma unroll
    for (int k = 0; k < O_DIM; ++k) t = fmaf(t1s[pl][k], W2[o * O_DIM + k], t);
    t = t > 0.f ? t : 0.2f * t;
    out[n * O_DIM + o] = t;
}

// ---------------------------------------------------------------------------
extern "C" void kernel_launch(void* const* d_in, const int* in_sizes, int n_in,
                              void* d_out, int out_size, void* d_ws, size_t ws_size,
                              hipStream_t stream)
{
    const float* points   = (const float*)d_in[0];
    const float* nuv      = (const float*)d_in[1];
    const float* features = (const float*)d_in[2];
    const float* W_in1    = (const float*)d_in[3];
    const float* b_in1    = (const float*)d_in[4];
    const float* W_in2    = (const float*)d_in[5];
    const float* b_in2    = (const float*)d_in[6];
    const float* gn_in_w  = (const float*)d_in[7];
    const float* gn_in_b  = (const float*)d_in[8];
    const float* cw1      = (const float*)d_in[9];
    const float* cb1      = (const float*)d_in[10];
    const float* cw2      = (const float*)d_in[11];
    const float* cb2      = (const float*)d_in[12];
    const float* W_out1   = (const float*)d_in[13];
    const float* b_out1   = (const float*)d_in[14];
    const float* W_out2   = (const float*)d_in[15];
    const float* b_out2   = (const float*)d_in[16];
    const float* gn_out_w = (const float*)d_in[17];
    const float* gn_out_b = (const float*)d_in[18];

    float* bufA = (float*)d_ws;                // N*64 floats
    float* bufB = bufA + N_PTS * H_DIM;        // N*64 floats
    float* outp = (float*)d_out;

    k_in_mlp <<<N_PTS / 4, 256, 0, stream>>>(features, W_in1, b_in1, W_in2, b_in2, bufA);
    k_gnorm  <<<NGROUPS, 1024, 0, stream>>>(bufA, gn_in_w, gn_in_b, bufB);
    k_conv   <<<N_PTS, 256, 0, stream>>>(points, nuv, cw1, cb1, cw2, cb2, bufB, bufA);
    k_out_mlp<<<N_PTS / 4, 256, 0, stream>>>(bufA, W_out1, b_out1, W_out2, b_out2, bufB);
    k_gnorm  <<<NGROUPS, 1024, 0, stream>>>(bufB, gn_out_w, gn_out_b, outp);
}